// Round 6
// baseline (840.469 us; speedup 1.0000x reference)
//
#include <hip/hip_runtime.h>

#define N_USER 100000
#define N_ITEM 200000
#define N_TOT  (N_USER + N_ITEM)
#define D      64
#define RPB    64                        // rows per bucket
#define NB     ((N_TOT + RPB - 1) / RPB) // 4688 buckets
#define NBLK_A 256                       // blocks for hist/bin passes
#define THR_A  512
#define SCAN_CHUNK 2048                  // tier-2 scan: 256 threads x 8

typedef unsigned long long u64;
typedef float vf4 __attribute__((ext_vector_type(4)));

__device__ __forceinline__ uint2 nt_load_u2(const uint2* p) {
    u64 raw = __builtin_nontemporal_load((const u64*)p);
    uint2 r; r.x = (unsigned)raw; r.y = (unsigned)(raw >> 32); return r;
}
__device__ __forceinline__ int nt_load_i(const int* p) {
    return __builtin_nontemporal_load(p);
}
__device__ __forceinline__ float nt_load_f(const float* p) {
    return __builtin_nontemporal_load(p);
}
__device__ __forceinline__ void nt_store_f4(float* p, float4 v) {
    vf4 t; t.x = v.x; t.y = v.y; t.z = v.z; t.w = v.w;
    __builtin_nontemporal_store(t, (vf4*)p);
}

// ================= tier-1: bucket binning =================

__global__ __launch_bounds__(THR_A) void hist_kernel(const int* __restrict__ rows,
                                                     int* __restrict__ hist, int nnz, int chunk) {
    __shared__ int h[NB];
    for (int k = threadIdx.x; k < NB; k += blockDim.x) h[k] = 0;
    __syncthreads();
    int lo = blockIdx.x * chunk;
    int hi = min(lo + chunk, nnz);
    for (int i = lo + threadIdx.x; i < hi; i += blockDim.x)
        atomicAdd(&h[nt_load_i(rows + i) >> 6], 1);
    __syncthreads();
    for (int k = threadIdx.x; k < NB; k += blockDim.x)
        hist[(size_t)blockIdx.x * NB + k] = h[k];
}

__global__ void bucket_tot_kernel(const int* __restrict__ hist, int* __restrict__ tot) {
    int k = blockIdx.x * blockDim.x + threadIdx.x;
    if (k >= NB) return;
    int s = 0;
    for (int b = 0; b < NBLK_A; ++b) s += hist[(size_t)b * NB + k];
    tot[k] = s;
}

__global__ __launch_bounds__(1024) void scan_kernel(const int* __restrict__ tot,
                                                    int* __restrict__ bstart, int nnz) {
    __shared__ int s[1024];
    const int t = threadIdx.x;
    const int PER = (NB + 1023) / 1024;   // 5
    int loc[8];
    int sum = 0;
    #pragma unroll
    for (int k = 0; k < PER; ++k) {
        int idx = t * PER + k;
        int v = (idx < NB) ? tot[idx] : 0;
        loc[k] = sum; sum += v;
    }
    s[t] = sum;
    __syncthreads();
    for (int off = 1; off < 1024; off <<= 1) {
        int v = (t >= off) ? s[t - off] : 0;
        __syncthreads();
        s[t] += v;
        __syncthreads();
    }
    int base = s[t] - sum;  // exclusive
    #pragma unroll
    for (int k = 0; k < PER; ++k) {
        int idx = t * PER + k;
        if (idx < NB) bstart[idx] = base + loc[k];
    }
    if (t == 1023) bstart[NB] = nnz;
}

__global__ void blockbase_kernel(int* __restrict__ hist, const int* __restrict__ bstart) {
    int k = blockIdx.x * blockDim.x + threadIdx.x;
    if (k >= NB) return;
    int base = bstart[k];
    for (int b = 0; b < NBLK_A; ++b) {
        size_t idx = (size_t)b * NB + k;
        int v = hist[idx];
        hist[idx] = base;
        base += v;
    }
}

__global__ __launch_bounds__(THR_A) void bin_kernel(const int* __restrict__ rows,
                                                    const int* __restrict__ cols,
                                                    const float* __restrict__ vals,
                                                    const int* __restrict__ hist,
                                                    uint2* __restrict__ eg, int nnz, int chunk) {
    __shared__ int cur[NB];
    for (int k = threadIdx.x; k < NB; k += blockDim.x)
        cur[k] = hist[(size_t)blockIdx.x * NB + k];
    __syncthreads();
    int lo = blockIdx.x * chunk;
    int hi = min(lo + chunk, nnz);
    for (int i = lo + threadIdx.x; i < hi; i += blockDim.x) {
        int r = nt_load_i(rows + i);
        int k = r >> 6;
        int slot = atomicAdd(&cur[k], 1);
        uint2 p;
        p.x = ((unsigned)(r & 63) << 19) | (unsigned)nt_load_i(cols + i);
        p.y = __float_as_uint(nt_load_f(vals + i));
        eg[slot] = p;      // normal store: wants L2 write-coalescing
    }
}

// per-bucket row sort: LDS hist -> 64-lane scan -> scatter to eg2 + row_start
__global__ __launch_bounds__(256) void rowsort_kernel(
    const uint2* __restrict__ eg, const int* __restrict__ bstart,
    uint2* __restrict__ eg2, int* __restrict__ row_start, int nnz)
{
    __shared__ int h[RPB];
    __shared__ int cur[RPB];
    const int k   = blockIdx.x;
    const int tid = threadIdx.x;
    const int s   = bstart[k];
    const int e   = bstart[k + 1];

    if (tid < RPB) h[tid] = 0;
    __syncthreads();
    for (int i = s + tid; i < e; i += 256)
        atomicAdd(&h[eg[i].x >> 19], 1);
    __syncthreads();
    if (tid < RPB) {   // wave 0 only
        int orig = h[tid];
        int v = orig;
        #pragma unroll
        for (int off = 1; off < RPB; off <<= 1) {
            int u = __shfl_up(v, off);
            if (tid >= off) v += u;
        }
        int excl = v - orig;
        cur[tid] = excl;
        int row = k * RPB + tid;
        if (row < N_TOT) row_start[row] = s + excl;
    }
    __syncthreads();
    for (int i = s + tid; i < e; i += 256) {
        uint2 p = nt_load_u2(eg + i);      // eg is dead after this kernel
        int ro = (int)(p.x >> 19);
        int slot = atomicAdd(&cur[ro], 1);
        eg2[s + slot] = p;                 // normal store: random 8B in 16KB window, wants L2
    }
    if (k == NB - 1 && tid == 0) row_start[N_TOT] = nnz;
}

// ================= fused gather: 16 lanes per row, float4 per lane =================
__global__ __launch_bounds__(256) void gather16_kernel(
    const float* __restrict__ users, const float* __restrict__ items,
    const int*   __restrict__ unb,   const float* __restrict__ uw,
    const int*   __restrict__ inb,   const float* __restrict__ iw,
    const int*   __restrict__ row_start, const uint2* __restrict__ eg,
    float* __restrict__ out)
{
    const int tid = threadIdx.x;
    const int grp = tid >> 4;          // 16 rows per block
    const int sub = tid & 15;
    const int row = blockIdx.x * 16 + grp;
    if (row >= N_TOT) return;
    const int d0 = sub * 4;

    float4 acc;
    if (row < N_USER) {
        acc = *reinterpret_cast<const float4*>(&users[(size_t)row * D + d0]);
        const int*   nb = unb + (size_t)row * 10;
        const float* w  = uw  + (size_t)row * 10;
        #pragma unroll
        for (int q = 0; q < 10; ++q) {
            float4 v = *reinterpret_cast<const float4*>(&users[(size_t)nb[q] * D + d0]);
            float wq = w[q];
            acc.x += wq * v.x; acc.y += wq * v.y; acc.z += wq * v.z; acc.w += wq * v.w;
        }
    } else {
        int r = row - N_USER;
        acc = *reinterpret_cast<const float4*>(&items[(size_t)r * D + d0]);
        const int*   nb = inb + (size_t)r * 10;
        const float* w  = iw  + (size_t)r * 10;
        #pragma unroll
        for (int q = 0; q < 10; ++q) {
            float4 v = *reinterpret_cast<const float4*>(&items[(size_t)nb[q] * D + d0]);
            float wq = w[q];
            acc.x += wq * v.x; acc.y += wq * v.y; acc.z += wq * v.z; acc.w += wq * v.w;
        }
    }

    const int s = row_start[row];
    const int e = row_start[row + 1];
    int i = s;
    for (; i + 7 < e; i += 8) {
        uint2 p[8];
        #pragma unroll
        for (int j = 0; j < 8; ++j) p[j] = nt_load_u2(eg + i + j);
        const float* sp[8];
        #pragma unroll
        for (int j = 0; j < 8; ++j) {
            int c = (int)(p[j].x & 0x7FFFFu);
            sp[j] = (c < N_USER) ? users + (size_t)c * D : items + (size_t)(c - N_USER) * D;
        }
        float4 v[8];
        #pragma unroll
        for (int j = 0; j < 8; ++j) v[j] = *reinterpret_cast<const float4*>(sp[j] + d0);
        #pragma unroll
        for (int j = 0; j < 8; ++j) {
            float a = __uint_as_float(p[j].y);
            acc.x += a * v[j].x; acc.y += a * v[j].y; acc.z += a * v[j].z; acc.w += a * v[j].w;
        }
    }
    for (; i < e; ++i) {
        uint2 p = nt_load_u2(eg + i);
        int c = (int)(p.x & 0x7FFFFu);
        const float* src = (c < N_USER) ? users + (size_t)c * D : items + (size_t)(c - N_USER) * D;
        float4 v = *reinterpret_cast<const float4*>(src + d0);
        float a = __uint_as_float(p.y);
        acc.x += a * v.x; acc.y += a * v.y; acc.z += a * v.z; acc.w += a * v.w;
    }

    nt_store_f4(&out[(size_t)row * D + d0], acc);
}

// ================= tier-2: round-2 CSR build + gather16 =================

__global__ void count_kernel(const int* __restrict__ rows, int* __restrict__ cnt, int nnz) {
    int i = blockIdx.x * blockDim.x + threadIdx.x;
    int stride = gridDim.x * blockDim.x;
    for (; i < nnz; i += stride) atomicAdd(&cnt[rows[i]], 1);
}

__global__ void scan_block_sums(const int* __restrict__ cnt, int* __restrict__ bsum, int n) {
    __shared__ int sdata[256];
    int base = blockIdx.x * SCAN_CHUNK;
    int s = 0;
    for (int t = threadIdx.x; t < SCAN_CHUNK; t += 256) {
        int idx = base + t;
        s += (idx < n) ? cnt[idx] : 0;
    }
    sdata[threadIdx.x] = s;
    __syncthreads();
    for (int off = 128; off > 0; off >>= 1) {
        if (threadIdx.x < off) sdata[threadIdx.x] += sdata[threadIdx.x + off];
        __syncthreads();
    }
    if (threadIdx.x == 0) bsum[blockIdx.x] = sdata[0];
}

__global__ void scan_bsum_kernel(int* __restrict__ bsum, int nb) {
    if (threadIdx.x == 0 && blockIdx.x == 0) {
        int acc = 0;
        for (int i = 0; i < nb; ++i) { int v = bsum[i]; bsum[i] = acc; acc += v; }
    }
}

__global__ void scan_final(const int* __restrict__ cnt, const int* __restrict__ bsum,
                           int* __restrict__ row_start, int n, int nnz) {
    __shared__ int sums[256];
    int b = blockIdx.x, t = threadIdx.x;
    int base = b * SCAN_CHUNK;
    int loc[8];
    int s = 0;
    #pragma unroll
    for (int k = 0; k < 8; ++k) {
        int idx = base + t * 8 + k;
        int v = (idx < n) ? cnt[idx] : 0;
        loc[k] = s; s += v;
    }
    sums[t] = s;
    __syncthreads();
    for (int off = 1; off < 256; off <<= 1) {
        int v = (t >= off) ? sums[t - off] : 0;
        __syncthreads();
        sums[t] += v;
        __syncthreads();
    }
    int off0 = bsum[b] + (sums[t] - s);
    #pragma unroll
    for (int k = 0; k < 8; ++k) {
        int idx = base + t * 8 + k;
        if (idx < n) row_start[idx] = off0 + loc[k];
    }
    if (b == gridDim.x - 1 && t == 255) row_start[n] = nnz;
}

__global__ void fill_kernel(const int* __restrict__ rows, const int* __restrict__ cols,
                            const float* __restrict__ vals, const int* __restrict__ row_start,
                            int* __restrict__ pos, uint2* __restrict__ eg, int nnz) {
    int i = blockIdx.x * blockDim.x + threadIdx.x;
    int stride = gridDim.x * blockDim.x;
    for (; i < nnz; i += stride) {
        int r = rows[i];
        int p = atomicAdd(&pos[r], 1);
        uint2 e;
        e.x = (unsigned)cols[i];
        e.y = __float_as_uint(vals[i]);
        eg[row_start[r] + p] = e;
    }
}

// ================= tier-3 fallback: scatter =================
__global__ __launch_bounds__(256) void base_neighbor_kernel(
    const float* __restrict__ users, const float* __restrict__ items,
    const int*   __restrict__ unb,   const float* __restrict__ uw,
    const int*   __restrict__ inb,   const float* __restrict__ iw,
    float* __restrict__ out)
{
    int gtid = blockIdx.x * blockDim.x + threadIdx.x;
    int row  = gtid >> 6;
    int lane = gtid & 63;
    if (row >= N_TOT) return;
    float acc;
    if (row < N_USER) {
        acc = users[(size_t)row * D + lane];
        const int*   nb = unb + (size_t)row * 10;
        const float* w  = uw  + (size_t)row * 10;
        #pragma unroll
        for (int q = 0; q < 10; ++q) acc += w[q] * users[(size_t)nb[q] * D + lane];
    } else {
        int r = row - N_USER;
        acc = items[(size_t)r * D + lane];
        const int*   nb = inb + (size_t)r * 10;
        const float* w  = iw  + (size_t)r * 10;
        #pragma unroll
        for (int q = 0; q < 10; ++q) acc += w[q] * items[(size_t)nb[q] * D + lane];
    }
    out[(size_t)row * D + lane] = acc;
}

__global__ __launch_bounds__(256) void edge_scatter_kernel(
    const float* __restrict__ users, const float* __restrict__ items,
    const int*   __restrict__ rows,  const int* __restrict__ cols,
    const float* __restrict__ vals,
    float* __restrict__ out, int nnz)
{
    int gtid = blockIdx.x * blockDim.x + threadIdx.x;
    int e    = gtid >> 6;
    int lane = gtid & 63;
    if (e >= nnz) return;
    int   r = rows[e];
    int   c = cols[e];
    float v = vals[e];
    const float* src = (c < N_USER) ? (users + (size_t)c * D)
                                    : (items + (size_t)(c - N_USER) * D);
    atomicAdd(&out[(size_t)r * D + lane], v * src[lane]);
}

extern "C" void kernel_launch(void* const* d_in, const int* in_sizes, int n_in,
                              void* d_out, int out_size, void* d_ws, size_t ws_size,
                              hipStream_t stream) {
    const float* users = (const float*)d_in[0];
    const float* items = (const float*)d_in[1];
    const int*   unb   = (const int*)  d_in[2];
    const float* uw    = (const float*)d_in[3];
    const int*   inb   = (const int*)  d_in[4];
    const float* iw    = (const float*)d_in[5];
    const int*   grow  = (const int*)  d_in[6];
    const int*   gcol  = (const int*)  d_in[7];
    const float* gval  = (const float*)d_in[8];
    float* out = (float*)d_out;

    const int nnz = in_sizes[6];

    const size_t A = 255;
    const size_t sz_eg       = (((size_t)nnz * 8) + A) & ~A;
    const size_t sz_eg2      = sz_eg;
    const size_t sz_hist     = (((size_t)NBLK_A * NB * 4) + A) & ~A;
    const size_t sz_tot      = (((size_t)NB * 4) + A) & ~A;
    const size_t sz_bstart   = (((size_t)(NB + 1) * 4) + A) & ~A;
    const size_t sz_rowstart = (((size_t)(N_TOT + 1) * 4) + A) & ~A;
    const size_t need1 = sz_eg + sz_eg2 + sz_hist + sz_tot + sz_bstart + sz_rowstart;

    const size_t sz_cnt  = (((size_t)N_TOT * 4) + A) & ~A;
    const int    nb2     = (N_TOT + SCAN_CHUNK - 1) / SCAN_CHUNK;
    const size_t sz_bsum = (((size_t)nb2 * 4) + A) & ~A;
    const size_t need2 = sz_eg + sz_rowstart + sz_cnt + sz_bsum;

    const int g16_grid = (N_TOT + 15) / 16;

    if (ws_size >= need1) {
        char* wsp = (char*)d_ws;
        uint2* eg        = (uint2*)wsp;  wsp += sz_eg;
        uint2* eg2       = (uint2*)wsp;  wsp += sz_eg2;
        int*   hist      = (int*)wsp;    wsp += sz_hist;
        int*   tot       = (int*)wsp;    wsp += sz_tot;
        int*   bstart    = (int*)wsp;    wsp += sz_bstart;
        int*   row_start = (int*)wsp;

        const int chunk = (nnz + NBLK_A - 1) / NBLK_A;

        hist_kernel<<<NBLK_A, THR_A, 0, stream>>>(grow, hist, nnz, chunk);
        bucket_tot_kernel<<<(NB + 255) / 256, 256, 0, stream>>>(hist, tot);
        scan_kernel<<<1, 1024, 0, stream>>>(tot, bstart, nnz);
        blockbase_kernel<<<(NB + 255) / 256, 256, 0, stream>>>(hist, bstart);
        bin_kernel<<<NBLK_A, THR_A, 0, stream>>>(grow, gcol, gval, hist, eg, nnz, chunk);
        rowsort_kernel<<<NB, 256, 0, stream>>>(eg, bstart, eg2, row_start, nnz);
        gather16_kernel<<<g16_grid, 256, 0, stream>>>(users, items, unb, uw, inb, iw,
                                                      row_start, eg2, out);
    } else if (ws_size >= need2) {
        char* wsp = (char*)d_ws;
        uint2* eg        = (uint2*)wsp;  wsp += sz_eg;
        int*   row_start = (int*)wsp;    wsp += sz_rowstart;
        int*   cnt       = (int*)wsp;    wsp += sz_cnt;
        int*   bsum      = (int*)wsp;

        hipMemsetAsync(cnt, 0, (size_t)N_TOT * 4, stream);
        count_kernel<<<2048, 256, 0, stream>>>(grow, cnt, nnz);
        scan_block_sums<<<nb2, 256, 0, stream>>>(cnt, bsum, N_TOT);
        scan_bsum_kernel<<<1, 64, 0, stream>>>(bsum, nb2);
        scan_final<<<nb2, 256, 0, stream>>>(cnt, bsum, row_start, N_TOT, nnz);
        hipMemsetAsync(cnt, 0, (size_t)N_TOT * 4, stream);
        fill_kernel<<<2048, 256, 0, stream>>>(grow, gcol, gval, row_start, cnt, eg, nnz);
        gather16_kernel<<<g16_grid, 256, 0, stream>>>(users, items, unb, uw, inb, iw,
                                                      row_start, eg, out);
    } else {
        int grid = (int)(((long long)N_TOT * 64 + 255) / 256);
        base_neighbor_kernel<<<grid, 256, 0, stream>>>(users, items, unb, uw, inb, iw, out);
        long long ethreads = (long long)nnz * 64;
        long long egrid = (ethreads + 255) / 256;
        edge_scatter_kernel<<<(int)egrid, 256, 0, stream>>>(users, items, grow, gcol, gval, out, nnz);
    }
}

// Round 7
// 607.230 us; speedup vs baseline: 1.3841x; 1.3841x over previous
//
#include <hip/hip_runtime.h>

#define N_USER 100000
#define N_ITEM 200000
#define N_TOT  (N_USER + N_ITEM)
#define D      64
#define RPB    64                        // rows per bucket
#define NB     ((N_TOT + RPB - 1) / RPB) // 4688 buckets
#define NBLK_A 256                       // blocks for hist/bin passes
#define THR_A  512
#define SCAN_CHUNK 2048                  // tier-2 scan: 256 threads x 8

__device__ __forceinline__ unsigned short f2bf(float f) {
    unsigned b = __float_as_uint(f);
    unsigned r = (b + 0x7FFFu + ((b >> 16) & 1u)) >> 16;   // round-to-nearest-even
    return (unsigned short)r;
}
__device__ __forceinline__ float bf2f(unsigned short u) {
    return __uint_as_float(((unsigned)u) << 16);
}

// ================= emb -> bf16 conversion =================
__global__ __launch_bounds__(256) void conv_kernel(const float* __restrict__ users,
                                                   const float* __restrict__ items,
                                                   ushort* __restrict__ emb16) {
    size_t i = (size_t)blockIdx.x * blockDim.x + threadIdx.x;   // quad index
    const size_t total = (size_t)N_TOT * D / 4;
    if (i >= total) return;
    size_t e0 = i * 4;
    const size_t usz = (size_t)N_USER * D;
    const float* src = (e0 < usz) ? users + e0 : items + (e0 - usz);
    float4 v = *reinterpret_cast<const float4*>(src);
    ushort4 o;
    o.x = f2bf(v.x); o.y = f2bf(v.y); o.z = f2bf(v.z); o.w = f2bf(v.w);
    *reinterpret_cast<ushort4*>(emb16 + e0) = o;
}

// ================= bucket binning =================

__global__ __launch_bounds__(THR_A) void hist_kernel(const int* __restrict__ rows,
                                                     int* __restrict__ hist, int nnz, int chunk) {
    __shared__ int h[NB];
    for (int k = threadIdx.x; k < NB; k += blockDim.x) h[k] = 0;
    __syncthreads();
    int lo = blockIdx.x * chunk;
    int hi = min(lo + chunk, nnz);
    for (int i = lo + threadIdx.x; i < hi; i += blockDim.x)
        atomicAdd(&h[rows[i] >> 6], 1);
    __syncthreads();
    for (int k = threadIdx.x; k < NB; k += blockDim.x)
        hist[(size_t)blockIdx.x * NB + k] = h[k];
}

__global__ void bucket_tot_kernel(const int* __restrict__ hist, int* __restrict__ tot) {
    int k = blockIdx.x * blockDim.x + threadIdx.x;
    if (k >= NB) return;
    int s = 0;
    for (int b = 0; b < NBLK_A; ++b) s += hist[(size_t)b * NB + k];
    tot[k] = s;
}

__global__ __launch_bounds__(1024) void scan_kernel(const int* __restrict__ tot,
                                                    int* __restrict__ bstart, int nnz) {
    __shared__ int s[1024];
    const int t = threadIdx.x;
    const int PER = (NB + 1023) / 1024;   // 5
    int loc[8];
    int sum = 0;
    #pragma unroll
    for (int k = 0; k < PER; ++k) {
        int idx = t * PER + k;
        int v = (idx < NB) ? tot[idx] : 0;
        loc[k] = sum; sum += v;
    }
    s[t] = sum;
    __syncthreads();
    for (int off = 1; off < 1024; off <<= 1) {
        int v = (t >= off) ? s[t - off] : 0;
        __syncthreads();
        s[t] += v;
        __syncthreads();
    }
    int base = s[t] - sum;  // exclusive
    #pragma unroll
    for (int k = 0; k < PER; ++k) {
        int idx = t * PER + k;
        if (idx < NB) bstart[idx] = base + loc[k];
    }
    if (t == 1023) bstart[NB] = nnz;
}

__global__ void blockbase_kernel(int* __restrict__ hist, const int* __restrict__ bstart) {
    int k = blockIdx.x * blockDim.x + threadIdx.x;
    if (k >= NB) return;
    int base = bstart[k];
    for (int b = 0; b < NBLK_A; ++b) {
        size_t idx = (size_t)b * NB + k;
        int v = hist[idx];
        hist[idx] = base;
        base += v;
    }
}

__global__ __launch_bounds__(THR_A) void bin_kernel(const int* __restrict__ rows,
                                                    const int* __restrict__ cols,
                                                    const float* __restrict__ vals,
                                                    const int* __restrict__ hist,
                                                    uint2* __restrict__ eg, int nnz, int chunk) {
    __shared__ int cur[NB];
    for (int k = threadIdx.x; k < NB; k += blockDim.x)
        cur[k] = hist[(size_t)blockIdx.x * NB + k];
    __syncthreads();
    int lo = blockIdx.x * chunk;
    int hi = min(lo + chunk, nnz);
    for (int i = lo + threadIdx.x; i < hi; i += blockDim.x) {
        int r = rows[i];
        int k = r >> 6;
        int slot = atomicAdd(&cur[k], 1);
        uint2 p;
        p.x = ((unsigned)(r & 63) << 19) | (unsigned)cols[i];
        p.y = __float_as_uint(vals[i]);
        eg[slot] = p;
    }
}

// per-bucket row sort: LDS hist -> 64-lane scan -> scatter to eg2 + row_start
__global__ __launch_bounds__(256) void rowsort_kernel(
    const uint2* __restrict__ eg, const int* __restrict__ bstart,
    uint2* __restrict__ eg2, int* __restrict__ row_start, int nnz)
{
    __shared__ int h[RPB];
    __shared__ int cur[RPB];
    const int k   = blockIdx.x;
    const int tid = threadIdx.x;
    const int s   = bstart[k];
    const int e   = bstart[k + 1];

    if (tid < RPB) h[tid] = 0;
    __syncthreads();
    for (int i = s + tid; i < e; i += 256)
        atomicAdd(&h[eg[i].x >> 19], 1);
    __syncthreads();
    if (tid < RPB) {   // wave 0 only
        int orig = h[tid];
        int v = orig;
        #pragma unroll
        for (int off = 1; off < RPB; off <<= 1) {
            int u = __shfl_up(v, off);
            if (tid >= off) v += u;
        }
        int excl = v - orig;
        cur[tid] = excl;
        int row = k * RPB + tid;
        if (row < N_TOT) row_start[row] = s + excl;
    }
    __syncthreads();
    for (int i = s + tid; i < e; i += 256) {
        uint2 p = eg[i];
        int ro = (int)(p.x >> 19);
        int slot = atomicAdd(&cur[ro], 1);
        eg2[s + slot] = p;
    }
    if (k == NB - 1 && tid == 0) row_start[N_TOT] = nnz;
}

// ================= fused gather, bf16 sources: 16 lanes/row, 4 d's/lane =================
__global__ __launch_bounds__(256) void gather16_bf16_kernel(
    const float* __restrict__ users, const float* __restrict__ items,
    const ushort* __restrict__ emb16,
    const int*   __restrict__ unb,   const float* __restrict__ uw,
    const int*   __restrict__ inb,   const float* __restrict__ iw,
    const int*   __restrict__ row_start, const uint2* __restrict__ eg,
    float* __restrict__ out)
{
    const int tid = threadIdx.x;
    const int grp = tid >> 4;
    const int sub = tid & 15;
    const int row = blockIdx.x * 16 + grp;
    if (row >= N_TOT) return;
    const int d0 = sub * 4;

    float4 acc;
    if (row < N_USER) {
        acc = *reinterpret_cast<const float4*>(&users[(size_t)row * D + d0]);
        const int*   nb = unb + (size_t)row * 10;
        const float* w  = uw  + (size_t)row * 10;
        #pragma unroll
        for (int q = 0; q < 10; ++q) {
            ushort4 u = *reinterpret_cast<const ushort4*>(emb16 + (size_t)nb[q] * D + d0);
            float wq = w[q];
            acc.x += wq * bf2f(u.x); acc.y += wq * bf2f(u.y);
            acc.z += wq * bf2f(u.z); acc.w += wq * bf2f(u.w);
        }
    } else {
        int r = row - N_USER;
        acc = *reinterpret_cast<const float4*>(&items[(size_t)r * D + d0]);
        const int*   nb = inb + (size_t)r * 10;
        const float* w  = iw  + (size_t)r * 10;
        #pragma unroll
        for (int q = 0; q < 10; ++q) {
            ushort4 u = *reinterpret_cast<const ushort4*>(emb16 + ((size_t)nb[q] + N_USER) * D + d0);
            float wq = w[q];
            acc.x += wq * bf2f(u.x); acc.y += wq * bf2f(u.y);
            acc.z += wq * bf2f(u.z); acc.w += wq * bf2f(u.w);
        }
    }

    const int s = row_start[row];
    const int e = row_start[row + 1];
    int i = s;
    for (; i + 7 < e; i += 8) {
        uint2 p[8];
        #pragma unroll
        for (int j = 0; j < 8; ++j) p[j] = eg[i + j];
        ushort4 u[8];
        #pragma unroll
        for (int j = 0; j < 8; ++j) {
            int c = (int)(p[j].x & 0x7FFFFu);
            u[j] = *reinterpret_cast<const ushort4*>(emb16 + (size_t)c * D + d0);
        }
        #pragma unroll
        for (int j = 0; j < 8; ++j) {
            float a = __uint_as_float(p[j].y);
            acc.x += a * bf2f(u[j].x); acc.y += a * bf2f(u[j].y);
            acc.z += a * bf2f(u[j].z); acc.w += a * bf2f(u[j].w);
        }
    }
    for (; i < e; ++i) {
        uint2 p = eg[i];
        int c = (int)(p.x & 0x7FFFFu);
        ushort4 u = *reinterpret_cast<const ushort4*>(emb16 + (size_t)c * D + d0);
        float a = __uint_as_float(p.y);
        acc.x += a * bf2f(u.x); acc.y += a * bf2f(u.y);
        acc.z += a * bf2f(u.z); acc.w += a * bf2f(u.w);
    }

    *reinterpret_cast<float4*>(&out[(size_t)row * D + d0]) = acc;
}

// ================= tier-1 fp32 gather (round-5 proven) =================
__global__ __launch_bounds__(256) void gather16_kernel(
    const float* __restrict__ users, const float* __restrict__ items,
    const int*   __restrict__ unb,   const float* __restrict__ uw,
    const int*   __restrict__ inb,   const float* __restrict__ iw,
    const int*   __restrict__ row_start, const uint2* __restrict__ eg,
    float* __restrict__ out)
{
    const int tid = threadIdx.x;
    const int grp = tid >> 4;
    const int sub = tid & 15;
    const int row = blockIdx.x * 16 + grp;
    if (row >= N_TOT) return;
    const int d0 = sub * 4;

    float4 acc;
    if (row < N_USER) {
        acc = *reinterpret_cast<const float4*>(&users[(size_t)row * D + d0]);
        const int*   nb = unb + (size_t)row * 10;
        const float* w  = uw  + (size_t)row * 10;
        #pragma unroll
        for (int q = 0; q < 10; ++q) {
            float4 v = *reinterpret_cast<const float4*>(&users[(size_t)nb[q] * D + d0]);
            float wq = w[q];
            acc.x += wq * v.x; acc.y += wq * v.y; acc.z += wq * v.z; acc.w += wq * v.w;
        }
    } else {
        int r = row - N_USER;
        acc = *reinterpret_cast<const float4*>(&items[(size_t)r * D + d0]);
        const int*   nb = inb + (size_t)r * 10;
        const float* w  = iw  + (size_t)r * 10;
        #pragma unroll
        for (int q = 0; q < 10; ++q) {
            float4 v = *reinterpret_cast<const float4*>(&items[(size_t)nb[q] * D + d0]);
            float wq = w[q];
            acc.x += wq * v.x; acc.y += wq * v.y; acc.z += wq * v.z; acc.w += wq * v.w;
        }
    }

    const int s = row_start[row];
    const int e = row_start[row + 1];
    int i = s;
    for (; i + 3 < e; i += 4) {
        uint2 p0 = eg[i], p1 = eg[i + 1], p2 = eg[i + 2], p3 = eg[i + 3];
        int c0 = (int)(p0.x & 0x7FFFFu), c1 = (int)(p1.x & 0x7FFFFu);
        int c2 = (int)(p2.x & 0x7FFFFu), c3 = (int)(p3.x & 0x7FFFFu);
        const float* s0 = (c0 < N_USER) ? users + (size_t)c0 * D : items + (size_t)(c0 - N_USER) * D;
        const float* s1 = (c1 < N_USER) ? users + (size_t)c1 * D : items + (size_t)(c1 - N_USER) * D;
        const float* s2 = (c2 < N_USER) ? users + (size_t)c2 * D : items + (size_t)(c2 - N_USER) * D;
        const float* s3 = (c3 < N_USER) ? users + (size_t)c3 * D : items + (size_t)(c3 - N_USER) * D;
        float4 v0 = *reinterpret_cast<const float4*>(s0 + d0);
        float4 v1 = *reinterpret_cast<const float4*>(s1 + d0);
        float4 v2 = *reinterpret_cast<const float4*>(s2 + d0);
        float4 v3 = *reinterpret_cast<const float4*>(s3 + d0);
        float a0 = __uint_as_float(p0.y), a1 = __uint_as_float(p1.y);
        float a2 = __uint_as_float(p2.y), a3 = __uint_as_float(p3.y);
        acc.x += a0 * v0.x; acc.y += a0 * v0.y; acc.z += a0 * v0.z; acc.w += a0 * v0.w;
        acc.x += a1 * v1.x; acc.y += a1 * v1.y; acc.z += a1 * v1.z; acc.w += a1 * v1.w;
        acc.x += a2 * v2.x; acc.y += a2 * v2.y; acc.z += a2 * v2.z; acc.w += a2 * v2.w;
        acc.x += a3 * v3.x; acc.y += a3 * v3.y; acc.z += a3 * v3.z; acc.w += a3 * v3.w;
    }
    for (; i < e; ++i) {
        uint2 p = eg[i];
        int c = (int)(p.x & 0x7FFFFu);
        const float* src = (c < N_USER) ? users + (size_t)c * D : items + (size_t)(c - N_USER) * D;
        float4 v = *reinterpret_cast<const float4*>(src + d0);
        float a = __uint_as_float(p.y);
        acc.x += a * v.x; acc.y += a * v.y; acc.z += a * v.z; acc.w += a * v.w;
    }

    *reinterpret_cast<float4*>(&out[(size_t)row * D + d0]) = acc;
}

// ================= tier-2: CSR build via global atomics =================

__global__ void count_kernel(const int* __restrict__ rows, int* __restrict__ cnt, int nnz) {
    int i = blockIdx.x * blockDim.x + threadIdx.x;
    int stride = gridDim.x * blockDim.x;
    for (; i < nnz; i += stride) atomicAdd(&cnt[rows[i]], 1);
}

__global__ void scan_block_sums(const int* __restrict__ cnt, int* __restrict__ bsum, int n) {
    __shared__ int sdata[256];
    int base = blockIdx.x * SCAN_CHUNK;
    int s = 0;
    for (int t = threadIdx.x; t < SCAN_CHUNK; t += 256) {
        int idx = base + t;
        s += (idx < n) ? cnt[idx] : 0;
    }
    sdata[threadIdx.x] = s;
    __syncthreads();
    for (int off = 128; off > 0; off >>= 1) {
        if (threadIdx.x < off) sdata[threadIdx.x] += sdata[threadIdx.x + off];
        __syncthreads();
    }
    if (threadIdx.x == 0) bsum[blockIdx.x] = sdata[0];
}

__global__ void scan_bsum_kernel(int* __restrict__ bsum, int nb) {
    if (threadIdx.x == 0 && blockIdx.x == 0) {
        int acc = 0;
        for (int i = 0; i < nb; ++i) { int v = bsum[i]; bsum[i] = acc; acc += v; }
    }
}

__global__ void scan_final(const int* __restrict__ cnt, const int* __restrict__ bsum,
                           int* __restrict__ row_start, int n, int nnz) {
    __shared__ int sums[256];
    int b = blockIdx.x, t = threadIdx.x;
    int base = b * SCAN_CHUNK;
    int loc[8];
    int s = 0;
    #pragma unroll
    for (int k = 0; k < 8; ++k) {
        int idx = base + t * 8 + k;
        int v = (idx < n) ? cnt[idx] : 0;
        loc[k] = s; s += v;
    }
    sums[t] = s;
    __syncthreads();
    for (int off = 1; off < 256; off <<= 1) {
        int v = (t >= off) ? sums[t - off] : 0;
        __syncthreads();
        sums[t] += v;
        __syncthreads();
    }
    int off0 = bsum[b] + (sums[t] - s);
    #pragma unroll
    for (int k = 0; k < 8; ++k) {
        int idx = base + t * 8 + k;
        if (idx < n) row_start[idx] = off0 + loc[k];
    }
    if (b == gridDim.x - 1 && t == 255) row_start[n] = nnz;
}

__global__ void fill_kernel(const int* __restrict__ rows, const int* __restrict__ cols,
                            const float* __restrict__ vals, const int* __restrict__ row_start,
                            int* __restrict__ pos, uint2* __restrict__ eg, int nnz) {
    int i = blockIdx.x * blockDim.x + threadIdx.x;
    int stride = gridDim.x * blockDim.x;
    for (; i < nnz; i += stride) {
        int r = rows[i];
        int p = atomicAdd(&pos[r], 1);
        uint2 e;
        e.x = (unsigned)cols[i];
        e.y = __float_as_uint(vals[i]);
        eg[row_start[r] + p] = e;
    }
}

// ================= tier-3 fallback: scatter =================
__global__ __launch_bounds__(256) void base_neighbor_kernel(
    const float* __restrict__ users, const float* __restrict__ items,
    const int*   __restrict__ unb,   const float* __restrict__ uw,
    const int*   __restrict__ inb,   const float* __restrict__ iw,
    float* __restrict__ out)
{
    int gtid = blockIdx.x * blockDim.x + threadIdx.x;
    int row  = gtid >> 6;
    int lane = gtid & 63;
    if (row >= N_TOT) return;
    float acc;
    if (row < N_USER) {
        acc = users[(size_t)row * D + lane];
        const int*   nb = unb + (size_t)row * 10;
        const float* w  = uw  + (size_t)row * 10;
        #pragma unroll
        for (int q = 0; q < 10; ++q) acc += w[q] * users[(size_t)nb[q] * D + lane];
    } else {
        int r = row - N_USER;
        acc = items[(size_t)r * D + lane];
        const int*   nb = inb + (size_t)r * 10;
        const float* w  = iw  + (size_t)r * 10;
        #pragma unroll
        for (int q = 0; q < 10; ++q) acc += w[q] * items[(size_t)nb[q] * D + lane];
    }
    out[(size_t)row * D + lane] = acc;
}

__global__ __launch_bounds__(256) void edge_scatter_kernel(
    const float* __restrict__ users, const float* __restrict__ items,
    const int*   __restrict__ rows,  const int* __restrict__ cols,
    const float* __restrict__ vals,
    float* __restrict__ out, int nnz)
{
    int gtid = blockIdx.x * blockDim.x + threadIdx.x;
    int e    = gtid >> 6;
    int lane = gtid & 63;
    if (e >= nnz) return;
    int   r = rows[e];
    int   c = cols[e];
    float v = vals[e];
    const float* src = (c < N_USER) ? (users + (size_t)c * D)
                                    : (items + (size_t)(c - N_USER) * D);
    atomicAdd(&out[(size_t)r * D + lane], v * src[lane]);
}

extern "C" void kernel_launch(void* const* d_in, const int* in_sizes, int n_in,
                              void* d_out, int out_size, void* d_ws, size_t ws_size,
                              hipStream_t stream) {
    const float* users = (const float*)d_in[0];
    const float* items = (const float*)d_in[1];
    const int*   unb   = (const int*)  d_in[2];
    const float* uw    = (const float*)d_in[3];
    const int*   inb   = (const int*)  d_in[4];
    const float* iw    = (const float*)d_in[5];
    const int*   grow  = (const int*)  d_in[6];
    const int*   gcol  = (const int*)  d_in[7];
    const float* gval  = (const float*)d_in[8];
    float* out = (float*)d_out;

    const int nnz = in_sizes[6];

    const size_t A = 255;
    const size_t sz_eg       = (((size_t)nnz * 8) + A) & ~A;
    const size_t sz_eg2      = sz_eg;
    const size_t sz_hist     = (((size_t)NBLK_A * NB * 4) + A) & ~A;
    const size_t sz_tot      = (((size_t)NB * 4) + A) & ~A;
    const size_t sz_bstart   = (((size_t)(NB + 1) * 4) + A) & ~A;
    const size_t sz_rowstart = (((size_t)(N_TOT + 1) * 4) + A) & ~A;
    const size_t sz_emb16    = (((size_t)N_TOT * D * 2) + A) & ~A;
    const size_t need1 = sz_eg + sz_eg2 + sz_hist + sz_tot + sz_bstart + sz_rowstart;
    const size_t need0 = need1 + sz_emb16;

    const size_t sz_cnt  = (((size_t)N_TOT * 4) + A) & ~A;
    const int    nb2     = (N_TOT + SCAN_CHUNK - 1) / SCAN_CHUNK;
    const size_t sz_bsum = (((size_t)nb2 * 4) + A) & ~A;
    const size_t need2 = sz_eg + sz_rowstart + sz_cnt + sz_bsum;

    const int g16_grid = (N_TOT + 15) / 16;

    if (ws_size >= need0) {
        char* wsp = (char*)d_ws;
        uint2*  eg        = (uint2*)wsp;  wsp += sz_eg;
        uint2*  eg2       = (uint2*)wsp;  wsp += sz_eg2;
        int*    hist      = (int*)wsp;    wsp += sz_hist;
        int*    tot       = (int*)wsp;    wsp += sz_tot;
        int*    bstart    = (int*)wsp;    wsp += sz_bstart;
        int*    row_start = (int*)wsp;    wsp += sz_rowstart;
        ushort* emb16     = (ushort*)wsp;

        const int chunk = (nnz + NBLK_A - 1) / NBLK_A;
        const int conv_grid = (int)(((size_t)N_TOT * D / 4 + 255) / 256);

        conv_kernel<<<conv_grid, 256, 0, stream>>>(users, items, emb16);
        hist_kernel<<<NBLK_A, THR_A, 0, stream>>>(grow, hist, nnz, chunk);
        bucket_tot_kernel<<<(NB + 255) / 256, 256, 0, stream>>>(hist, tot);
        scan_kernel<<<1, 1024, 0, stream>>>(tot, bstart, nnz);
        blockbase_kernel<<<(NB + 255) / 256, 256, 0, stream>>>(hist, bstart);
        bin_kernel<<<NBLK_A, THR_A, 0, stream>>>(grow, gcol, gval, hist, eg, nnz, chunk);
        rowsort_kernel<<<NB, 256, 0, stream>>>(eg, bstart, eg2, row_start, nnz);
        gather16_bf16_kernel<<<g16_grid, 256, 0, stream>>>(users, items, emb16,
                                                           unb, uw, inb, iw,
                                                           row_start, eg2, out);
    } else if (ws_size >= need1) {
        char* wsp = (char*)d_ws;
        uint2* eg        = (uint2*)wsp;  wsp += sz_eg;
        uint2* eg2       = (uint2*)wsp;  wsp += sz_eg2;
        int*   hist      = (int*)wsp;    wsp += sz_hist;
        int*   tot       = (int*)wsp;    wsp += sz_tot;
        int*   bstart    = (int*)wsp;    wsp += sz_bstart;
        int*   row_start = (int*)wsp;

        const int chunk = (nnz + NBLK_A - 1) / NBLK_A;

        hist_kernel<<<NBLK_A, THR_A, 0, stream>>>(grow, hist, nnz, chunk);
        bucket_tot_kernel<<<(NB + 255) / 256, 256, 0, stream>>>(hist, tot);
        scan_kernel<<<1, 1024, 0, stream>>>(tot, bstart, nnz);
        blockbase_kernel<<<(NB + 255) / 256, 256, 0, stream>>>(hist, bstart);
        bin_kernel<<<NBLK_A, THR_A, 0, stream>>>(grow, gcol, gval, hist, eg, nnz, chunk);
        rowsort_kernel<<<NB, 256, 0, stream>>>(eg, bstart, eg2, row_start, nnz);
        gather16_kernel<<<g16_grid, 256, 0, stream>>>(users, items, unb, uw, inb, iw,
                                                      row_start, eg2, out);
    } else if (ws_size >= need2) {
        char* wsp = (char*)d_ws;
        uint2* eg        = (uint2*)wsp;  wsp += sz_eg;
        int*   row_start = (int*)wsp;    wsp += sz_rowstart;
        int*   cnt       = (int*)wsp;    wsp += sz_cnt;
        int*   bsum      = (int*)wsp;

        hipMemsetAsync(cnt, 0, (size_t)N_TOT * 4, stream);
        count_kernel<<<2048, 256, 0, stream>>>(grow, cnt, nnz);
        scan_block_sums<<<nb2, 256, 0, stream>>>(cnt, bsum, N_TOT);
        scan_bsum_kernel<<<1, 64, 0, stream>>>(bsum, nb2);
        scan_final<<<nb2, 256, 0, stream>>>(cnt, bsum, row_start, N_TOT, nnz);
        hipMemsetAsync(cnt, 0, (size_t)N_TOT * 4, stream);
        fill_kernel<<<2048, 256, 0, stream>>>(grow, gcol, gval, row_start, cnt, eg, nnz);
        gather16_kernel<<<g16_grid, 256, 0, stream>>>(users, items, unb, uw, inb, iw,
                                                      row_start, eg, out);
    } else {
        int grid = (int)(((long long)N_TOT * 64 + 255) / 256);
        base_neighbor_kernel<<<grid, 256, 0, stream>>>(users, items, unb, uw, inb, iw, out);
        long long ethreads = (long long)nnz * 64;
        long long egrid = (ethreads + 255) / 256;
        edge_scatter_kernel<<<(int)egrid, 256, 0, stream>>>(users, items, grow, gcol, gval, out, nnz);
    }
}

// Round 8
// 600.047 us; speedup vs baseline: 1.4007x; 1.0120x over previous
//
#include <hip/hip_runtime.h>

#define N_USER 100000
#define N_ITEM 200000
#define N_TOT  (N_USER + N_ITEM)
#define D      64
#define RPB    256                       // rows per bucket
#define NB     ((N_TOT + RPB - 1) / RPB) // 1172 buckets
#define NBLK_A 256                       // blocks for hist/bin passes
#define THR_A  512
#define SCAN_CHUNK 2048                  // tier-2 scan: 256 threads x 8

__device__ __forceinline__ unsigned short f2bf(float f) {
    unsigned b = __float_as_uint(f);
    unsigned r = (b + 0x7FFFu + ((b >> 16) & 1u)) >> 16;   // round-to-nearest-even
    return (unsigned short)r;
}
__device__ __forceinline__ float bf2f(unsigned short u) {
    return __uint_as_float(((unsigned)u) << 16);
}

// ================= emb -> bf16 conversion =================
__global__ __launch_bounds__(256) void conv_kernel(const float* __restrict__ users,
                                                   const float* __restrict__ items,
                                                   ushort* __restrict__ emb16) {
    size_t i = (size_t)blockIdx.x * blockDim.x + threadIdx.x;   // quad index
    const size_t total = (size_t)N_TOT * D / 4;
    if (i >= total) return;
    size_t e0 = i * 4;
    const size_t usz = (size_t)N_USER * D;
    const float* src = (e0 < usz) ? users + e0 : items + (e0 - usz);
    float4 v = *reinterpret_cast<const float4*>(src);
    ushort4 o;
    o.x = f2bf(v.x); o.y = f2bf(v.y); o.z = f2bf(v.z); o.w = f2bf(v.w);
    *reinterpret_cast<ushort4*>(emb16 + e0) = o;
}

// ================= bucket binning =================

__global__ __launch_bounds__(THR_A) void hist_kernel(const int* __restrict__ rows,
                                                     int* __restrict__ hist, int nnz, int chunk) {
    __shared__ int h[NB];
    for (int k = threadIdx.x; k < NB; k += blockDim.x) h[k] = 0;
    __syncthreads();
    int lo = blockIdx.x * chunk;
    int hi = min(lo + chunk, nnz);
    for (int i = lo + threadIdx.x; i < hi; i += blockDim.x)
        atomicAdd(&h[rows[i] >> 8], 1);
    __syncthreads();
    for (int k = threadIdx.x; k < NB; k += blockDim.x)
        hist[(size_t)blockIdx.x * NB + k] = h[k];
}

__global__ void bucket_tot_kernel(const int* __restrict__ hist, int* __restrict__ tot) {
    int k = blockIdx.x * blockDim.x + threadIdx.x;
    if (k >= NB) return;
    int s = 0;
    for (int b = 0; b < NBLK_A; ++b) s += hist[(size_t)b * NB + k];
    tot[k] = s;
}

__global__ __launch_bounds__(1024) void scan_kernel(const int* __restrict__ tot,
                                                    int* __restrict__ bstart, int nnz) {
    __shared__ int s[1024];
    const int t = threadIdx.x;
    const int PER = (NB + 1023) / 1024;   // 2
    int loc[4];
    int sum = 0;
    #pragma unroll
    for (int k = 0; k < PER; ++k) {
        int idx = t * PER + k;
        int v = (idx < NB) ? tot[idx] : 0;
        loc[k] = sum; sum += v;
    }
    s[t] = sum;
    __syncthreads();
    for (int off = 1; off < 1024; off <<= 1) {
        int v = (t >= off) ? s[t - off] : 0;
        __syncthreads();
        s[t] += v;
        __syncthreads();
    }
    int base = s[t] - sum;  // exclusive
    #pragma unroll
    for (int k = 0; k < PER; ++k) {
        int idx = t * PER + k;
        if (idx < NB) bstart[idx] = base + loc[k];
    }
    if (t == 1023) bstart[NB] = nnz;
}

__global__ void blockbase_kernel(int* __restrict__ hist, const int* __restrict__ bstart) {
    int k = blockIdx.x * blockDim.x + threadIdx.x;
    if (k >= NB) return;
    int base = bstart[k];
    for (int b = 0; b < NBLK_A; ++b) {
        size_t idx = (size_t)b * NB + k;
        int v = hist[idx];
        hist[idx] = base;
        base += v;
    }
}

__global__ __launch_bounds__(THR_A) void bin_kernel(const int* __restrict__ rows,
                                                    const int* __restrict__ cols,
                                                    const float* __restrict__ vals,
                                                    const int* __restrict__ hist,
                                                    uint2* __restrict__ eg, int nnz, int chunk) {
    __shared__ int cur[NB];
    for (int k = threadIdx.x; k < NB; k += blockDim.x)
        cur[k] = hist[(size_t)blockIdx.x * NB + k];
    __syncthreads();
    int lo = blockIdx.x * chunk;
    int hi = min(lo + chunk, nnz);
    for (int i = lo + threadIdx.x; i < hi; i += blockDim.x) {
        int r = rows[i];
        int k = r >> 8;
        int slot = atomicAdd(&cur[k], 1);
        uint2 p;
        p.x = ((unsigned)(r & 255) << 19) | (unsigned)cols[i];
        p.y = __float_as_uint(vals[i]);
        eg[slot] = p;
    }
}

// per-bucket row sort: LDS hist -> 256-entry block scan -> scatter to eg2 + row_start
__global__ __launch_bounds__(256) void rowsort_kernel(
    const uint2* __restrict__ eg, const int* __restrict__ bstart,
    uint2* __restrict__ eg2, int* __restrict__ row_start, int nnz)
{
    __shared__ int h[RPB];
    __shared__ int sc[RPB];
    __shared__ int cur[RPB];
    const int k   = blockIdx.x;
    const int tid = threadIdx.x;
    const int s   = bstart[k];
    const int e   = bstart[k + 1];

    h[tid] = 0;
    __syncthreads();
    for (int i = s + tid; i < e; i += 256)
        atomicAdd(&h[eg[i].x >> 19], 1);
    __syncthreads();
    int orig = h[tid];
    sc[tid] = orig;
    __syncthreads();
    #pragma unroll
    for (int off = 1; off < RPB; off <<= 1) {
        int v = (tid >= off) ? sc[tid - off] : 0;
        __syncthreads();
        sc[tid] += v;
        __syncthreads();
    }
    int excl = sc[tid] - orig;
    cur[tid] = excl;
    {
        int row = k * RPB + tid;
        if (row < N_TOT) row_start[row] = s + excl;
    }
    __syncthreads();
    for (int i = s + tid; i < e; i += 256) {
        uint2 p = eg[i];
        int ro = (int)(p.x >> 19);
        int slot = atomicAdd(&cur[ro], 1);
        eg2[s + slot] = p;
    }
    if (k == NB - 1 && tid == 0) row_start[N_TOT] = nnz;
}

// ================= fused gather, bf16 sources: 16 lanes/row, 4 d's/lane =================
__global__ __launch_bounds__(256) void gather16_bf16_kernel(
    const float* __restrict__ users, const float* __restrict__ items,
    const ushort* __restrict__ emb16,
    const int*   __restrict__ unb,   const float* __restrict__ uw,
    const int*   __restrict__ inb,   const float* __restrict__ iw,
    const int*   __restrict__ row_start, const uint2* __restrict__ eg,
    float* __restrict__ out)
{
    const int tid = threadIdx.x;
    const int grp = tid >> 4;
    const int sub = tid & 15;
    const int row = blockIdx.x * 16 + grp;
    if (row >= N_TOT) return;
    const int d0 = sub * 4;

    float4 acc;
    if (row < N_USER) {
        acc = *reinterpret_cast<const float4*>(&users[(size_t)row * D + d0]);
        const int*   nb = unb + (size_t)row * 10;
        const float* w  = uw  + (size_t)row * 10;
        #pragma unroll
        for (int q = 0; q < 10; ++q) {
            ushort4 u = *reinterpret_cast<const ushort4*>(emb16 + (size_t)nb[q] * D + d0);
            float wq = w[q];
            acc.x += wq * bf2f(u.x); acc.y += wq * bf2f(u.y);
            acc.z += wq * bf2f(u.z); acc.w += wq * bf2f(u.w);
        }
    } else {
        int r = row - N_USER;
        acc = *reinterpret_cast<const float4*>(&items[(size_t)r * D + d0]);
        const int*   nb = inb + (size_t)r * 10;
        const float* w  = iw  + (size_t)r * 10;
        #pragma unroll
        for (int q = 0; q < 10; ++q) {
            ushort4 u = *reinterpret_cast<const ushort4*>(emb16 + ((size_t)nb[q] + N_USER) * D + d0);
            float wq = w[q];
            acc.x += wq * bf2f(u.x); acc.y += wq * bf2f(u.y);
            acc.z += wq * bf2f(u.z); acc.w += wq * bf2f(u.w);
        }
    }

    const int s = row_start[row];
    const int e = row_start[row + 1];
    int i = s;
    for (; i + 7 < e; i += 8) {
        uint2 p[8];
        #pragma unroll
        for (int j = 0; j < 8; ++j) p[j] = eg[i + j];
        ushort4 u[8];
        #pragma unroll
        for (int j = 0; j < 8; ++j) {
            int c = (int)(p[j].x & 0x7FFFFu);
            u[j] = *reinterpret_cast<const ushort4*>(emb16 + (size_t)c * D + d0);
        }
        #pragma unroll
        for (int j = 0; j < 8; ++j) {
            float a = __uint_as_float(p[j].y);
            acc.x += a * bf2f(u[j].x); acc.y += a * bf2f(u[j].y);
            acc.z += a * bf2f(u[j].z); acc.w += a * bf2f(u[j].w);
        }
    }
    for (; i < e; ++i) {
        uint2 p = eg[i];
        int c = (int)(p.x & 0x7FFFFu);
        ushort4 u = *reinterpret_cast<const ushort4*>(emb16 + (size_t)c * D + d0);
        float a = __uint_as_float(p.y);
        acc.x += a * bf2f(u.x); acc.y += a * bf2f(u.y);
        acc.z += a * bf2f(u.z); acc.w += a * bf2f(u.w);
    }

    *reinterpret_cast<float4*>(&out[(size_t)row * D + d0]) = acc;
}

// ================= tier-1 fp32 gather (fallback if ws too small for emb16) =================
__global__ __launch_bounds__(256) void gather16_kernel(
    const float* __restrict__ users, const float* __restrict__ items,
    const int*   __restrict__ unb,   const float* __restrict__ uw,
    const int*   __restrict__ inb,   const float* __restrict__ iw,
    const int*   __restrict__ row_start, const uint2* __restrict__ eg,
    float* __restrict__ out)
{
    const int tid = threadIdx.x;
    const int grp = tid >> 4;
    const int sub = tid & 15;
    const int row = blockIdx.x * 16 + grp;
    if (row >= N_TOT) return;
    const int d0 = sub * 4;

    float4 acc;
    if (row < N_USER) {
        acc = *reinterpret_cast<const float4*>(&users[(size_t)row * D + d0]);
        const int*   nb = unb + (size_t)row * 10;
        const float* w  = uw  + (size_t)row * 10;
        #pragma unroll
        for (int q = 0; q < 10; ++q) {
            float4 v = *reinterpret_cast<const float4*>(&users[(size_t)nb[q] * D + d0]);
            float wq = w[q];
            acc.x += wq * v.x; acc.y += wq * v.y; acc.z += wq * v.z; acc.w += wq * v.w;
        }
    } else {
        int r = row - N_USER;
        acc = *reinterpret_cast<const float4*>(&items[(size_t)r * D + d0]);
        const int*   nb = inb + (size_t)r * 10;
        const float* w  = iw  + (size_t)r * 10;
        #pragma unroll
        for (int q = 0; q < 10; ++q) {
            float4 v = *reinterpret_cast<const float4*>(&items[(size_t)nb[q] * D + d0]);
            float wq = w[q];
            acc.x += wq * v.x; acc.y += wq * v.y; acc.z += wq * v.z; acc.w += wq * v.w;
        }
    }

    const int s = row_start[row];
    const int e = row_start[row + 1];
    int i = s;
    for (; i + 3 < e; i += 4) {
        uint2 p0 = eg[i], p1 = eg[i + 1], p2 = eg[i + 2], p3 = eg[i + 3];
        int c0 = (int)(p0.x & 0x7FFFFu), c1 = (int)(p1.x & 0x7FFFFu);
        int c2 = (int)(p2.x & 0x7FFFFu), c3 = (int)(p3.x & 0x7FFFFu);
        const float* s0 = (c0 < N_USER) ? users + (size_t)c0 * D : items + (size_t)(c0 - N_USER) * D;
        const float* s1 = (c1 < N_USER) ? users + (size_t)c1 * D : items + (size_t)(c1 - N_USER) * D;
        const float* s2 = (c2 < N_USER) ? users + (size_t)c2 * D : items + (size_t)(c2 - N_USER) * D;
        const float* s3 = (c3 < N_USER) ? users + (size_t)c3 * D : items + (size_t)(c3 - N_USER) * D;
        float4 v0 = *reinterpret_cast<const float4*>(s0 + d0);
        float4 v1 = *reinterpret_cast<const float4*>(s1 + d0);
        float4 v2 = *reinterpret_cast<const float4*>(s2 + d0);
        float4 v3 = *reinterpret_cast<const float4*>(s3 + d0);
        float a0 = __uint_as_float(p0.y), a1 = __uint_as_float(p1.y);
        float a2 = __uint_as_float(p2.y), a3 = __uint_as_float(p3.y);
        acc.x += a0 * v0.x; acc.y += a0 * v0.y; acc.z += a0 * v0.z; acc.w += a0 * v0.w;
        acc.x += a1 * v1.x; acc.y += a1 * v1.y; acc.z += a1 * v1.z; acc.w += a1 * v1.w;
        acc.x += a2 * v2.x; acc.y += a2 * v2.y; acc.z += a2 * v2.z; acc.w += a2 * v2.w;
        acc.x += a3 * v3.x; acc.y += a3 * v3.y; acc.z += a3 * v3.z; acc.w += a3 * v3.w;
    }
    for (; i < e; ++i) {
        uint2 p = eg[i];
        int c = (int)(p.x & 0x7FFFFu);
        const float* src = (c < N_USER) ? users + (size_t)c * D : items + (size_t)(c - N_USER) * D;
        float4 v = *reinterpret_cast<const float4*>(src + d0);
        float a = __uint_as_float(p.y);
        acc.x += a * v.x; acc.y += a * v.y; acc.z += a * v.z; acc.w += a * v.w;
    }

    *reinterpret_cast<float4*>(&out[(size_t)row * D + d0]) = acc;
}

// ================= tier-2: CSR build via global atomics =================

__global__ void count_kernel(const int* __restrict__ rows, int* __restrict__ cnt, int nnz) {
    int i = blockIdx.x * blockDim.x + threadIdx.x;
    int stride = gridDim.x * blockDim.x;
    for (; i < nnz; i += stride) atomicAdd(&cnt[rows[i]], 1);
}

__global__ void scan_block_sums(const int* __restrict__ cnt, int* __restrict__ bsum, int n) {
    __shared__ int sdata[256];
    int base = blockIdx.x * SCAN_CHUNK;
    int s = 0;
    for (int t = threadIdx.x; t < SCAN_CHUNK; t += 256) {
        int idx = base + t;
        s += (idx < n) ? cnt[idx] : 0;
    }
    sdata[threadIdx.x] = s;
    __syncthreads();
    for (int off = 128; off > 0; off >>= 1) {
        if (threadIdx.x < off) sdata[threadIdx.x] += sdata[threadIdx.x + off];
        __syncthreads();
    }
    if (threadIdx.x == 0) bsum[blockIdx.x] = sdata[0];
}

__global__ void scan_bsum_kernel(int* __restrict__ bsum, int nb) {
    if (threadIdx.x == 0 && blockIdx.x == 0) {
        int acc = 0;
        for (int i = 0; i < nb; ++i) { int v = bsum[i]; bsum[i] = acc; acc += v; }
    }
}

__global__ void scan_final(const int* __restrict__ cnt, const int* __restrict__ bsum,
                           int* __restrict__ row_start, int n, int nnz) {
    __shared__ int sums[256];
    int b = blockIdx.x, t = threadIdx.x;
    int base = b * SCAN_CHUNK;
    int loc[8];
    int s = 0;
    #pragma unroll
    for (int k = 0; k < 8; ++k) {
        int idx = base + t * 8 + k;
        int v = (idx < n) ? cnt[idx] : 0;
        loc[k] = s; s += v;
    }
    sums[t] = s;
    __syncthreads();
    for (int off = 1; off < 256; off <<= 1) {
        int v = (t >= off) ? sums[t - off] : 0;
        __syncthreads();
        sums[t] += v;
        __syncthreads();
    }
    int off0 = bsum[b] + (sums[t] - s);
    #pragma unroll
    for (int k = 0; k < 8; ++k) {
        int idx = base + t * 8 + k;
        if (idx < n) row_start[idx] = off0 + loc[k];
    }
    if (b == gridDim.x - 1 && t == 255) row_start[n] = nnz;
}

__global__ void fill_kernel(const int* __restrict__ rows, const int* __restrict__ cols,
                            const float* __restrict__ vals, const int* __restrict__ row_start,
                            int* __restrict__ pos, uint2* __restrict__ eg, int nnz) {
    int i = blockIdx.x * blockDim.x + threadIdx.x;
    int stride = gridDim.x * blockDim.x;
    for (; i < nnz; i += stride) {
        int r = rows[i];
        int p = atomicAdd(&pos[r], 1);
        uint2 e;
        e.x = (unsigned)cols[i];
        e.y = __float_as_uint(vals[i]);
        eg[row_start[r] + p] = e;
    }
}

// ================= tier-3 fallback: scatter =================
__global__ __launch_bounds__(256) void base_neighbor_kernel(
    const float* __restrict__ users, const float* __restrict__ items,
    const int*   __restrict__ unb,   const float* __restrict__ uw,
    const int*   __restrict__ inb,   const float* __restrict__ iw,
    float* __restrict__ out)
{
    int gtid = blockIdx.x * blockDim.x + threadIdx.x;
    int row  = gtid >> 6;
    int lane = gtid & 63;
    if (row >= N_TOT) return;
    float acc;
    if (row < N_USER) {
        acc = users[(size_t)row * D + lane];
        const int*   nb = unb + (size_t)row * 10;
        const float* w  = uw  + (size_t)row * 10;
        #pragma unroll
        for (int q = 0; q < 10; ++q) acc += w[q] * users[(size_t)nb[q] * D + lane];
    } else {
        int r = row - N_USER;
        acc = items[(size_t)r * D + lane];
        const int*   nb = inb + (size_t)r * 10;
        const float* w  = iw  + (size_t)r * 10;
        #pragma unroll
        for (int q = 0; q < 10; ++q) acc += w[q] * items[(size_t)nb[q] * D + lane];
    }
    out[(size_t)row * D + lane] = acc;
}

__global__ __launch_bounds__(256) void edge_scatter_kernel(
    const float* __restrict__ users, const float* __restrict__ items,
    const int*   __restrict__ rows,  const int* __restrict__ cols,
    const float* __restrict__ vals,
    float* __restrict__ out, int nnz)
{
    int gtid = blockIdx.x * blockDim.x + threadIdx.x;
    int e    = gtid >> 6;
    int lane = gtid & 63;
    if (e >= nnz) return;
    int   r = rows[e];
    int   c = cols[e];
    float v = vals[e];
    const float* src = (c < N_USER) ? (users + (size_t)c * D)
                                    : (items + (size_t)(c - N_USER) * D);
    atomicAdd(&out[(size_t)r * D + lane], v * src[lane]);
}

extern "C" void kernel_launch(void* const* d_in, const int* in_sizes, int n_in,
                              void* d_out, int out_size, void* d_ws, size_t ws_size,
                              hipStream_t stream) {
    const float* users = (const float*)d_in[0];
    const float* items = (const float*)d_in[1];
    const int*   unb   = (const int*)  d_in[2];
    const float* uw    = (const float*)d_in[3];
    const int*   inb   = (const int*)  d_in[4];
    const float* iw    = (const float*)d_in[5];
    const int*   grow  = (const int*)  d_in[6];
    const int*   gcol  = (const int*)  d_in[7];
    const float* gval  = (const float*)d_in[8];
    float* out = (float*)d_out;

    const int nnz = in_sizes[6];

    const size_t A = 255;
    const size_t sz_eg       = (((size_t)nnz * 8) + A) & ~A;
    const size_t sz_eg2      = sz_eg;
    const size_t sz_hist     = (((size_t)NBLK_A * NB * 4) + A) & ~A;
    const size_t sz_tot      = (((size_t)NB * 4) + A) & ~A;
    const size_t sz_bstart   = (((size_t)(NB + 1) * 4) + A) & ~A;
    const size_t sz_rowstart = (((size_t)(N_TOT + 1) * 4) + A) & ~A;
    const size_t sz_emb16    = (((size_t)N_TOT * D * 2) + A) & ~A;
    const size_t need1 = sz_eg + sz_eg2 + sz_hist + sz_tot + sz_bstart + sz_rowstart;
    const size_t need0 = need1 + sz_emb16;

    const size_t sz_cnt  = (((size_t)N_TOT * 4) + A) & ~A;
    const int    nb2     = (N_TOT + SCAN_CHUNK - 1) / SCAN_CHUNK;
    const size_t sz_bsum = (((size_t)nb2 * 4) + A) & ~A;
    const size_t need2 = sz_eg + sz_rowstart + sz_cnt + sz_bsum;

    const int g16_grid = (N_TOT + 15) / 16;

    if (ws_size >= need0) {
        char* wsp = (char*)d_ws;
        uint2*  eg        = (uint2*)wsp;  wsp += sz_eg;
        uint2*  eg2       = (uint2*)wsp;  wsp += sz_eg2;
        int*    hist      = (int*)wsp;    wsp += sz_hist;
        int*    tot       = (int*)wsp;    wsp += sz_tot;
        int*    bstart    = (int*)wsp;    wsp += sz_bstart;
        int*    row_start = (int*)wsp;    wsp += sz_rowstart;
        ushort* emb16     = (ushort*)wsp;

        const int chunk = (nnz + NBLK_A - 1) / NBLK_A;
        const int conv_grid = (int)(((size_t)N_TOT * D / 4 + 255) / 256);

        conv_kernel<<<conv_grid, 256, 0, stream>>>(users, items, emb16);
        hist_kernel<<<NBLK_A, THR_A, 0, stream>>>(grow, hist, nnz, chunk);
        bucket_tot_kernel<<<(NB + 255) / 256, 256, 0, stream>>>(hist, tot);
        scan_kernel<<<1, 1024, 0, stream>>>(tot, bstart, nnz);
        blockbase_kernel<<<(NB + 255) / 256, 256, 0, stream>>>(hist, bstart);
        bin_kernel<<<NBLK_A, THR_A, 0, stream>>>(grow, gcol, gval, hist, eg, nnz, chunk);
        rowsort_kernel<<<NB, 256, 0, stream>>>(eg, bstart, eg2, row_start, nnz);
        gather16_bf16_kernel<<<g16_grid, 256, 0, stream>>>(users, items, emb16,
                                                           unb, uw, inb, iw,
                                                           row_start, eg2, out);
    } else if (ws_size >= need1) {
        char* wsp = (char*)d_ws;
        uint2* eg        = (uint2*)wsp;  wsp += sz_eg;
        uint2* eg2       = (uint2*)wsp;  wsp += sz_eg2;
        int*   hist      = (int*)wsp;    wsp += sz_hist;
        int*   tot       = (int*)wsp;    wsp += sz_tot;
        int*   bstart    = (int*)wsp;    wsp += sz_bstart;
        int*   row_start = (int*)wsp;

        const int chunk = (nnz + NBLK_A - 1) / NBLK_A;

        hist_kernel<<<NBLK_A, THR_A, 0, stream>>>(grow, hist, nnz, chunk);
        bucket_tot_kernel<<<(NB + 255) / 256, 256, 0, stream>>>(hist, tot);
        scan_kernel<<<1, 1024, 0, stream>>>(tot, bstart, nnz);
        blockbase_kernel<<<(NB + 255) / 256, 256, 0, stream>>>(hist, bstart);
        bin_kernel<<<NBLK_A, THR_A, 0, stream>>>(grow, gcol, gval, hist, eg, nnz, chunk);
        rowsort_kernel<<<NB, 256, 0, stream>>>(eg, bstart, eg2, row_start, nnz);
        gather16_kernel<<<g16_grid, 256, 0, stream>>>(users, items, unb, uw, inb, iw,
                                                      row_start, eg2, out);
    } else if (ws_size >= need2) {
        char* wsp = (char*)d_ws;
        uint2* eg        = (uint2*)wsp;  wsp += sz_eg;
        int*   row_start = (int*)wsp;    wsp += sz_rowstart;
        int*   cnt       = (int*)wsp;    wsp += sz_cnt;
        int*   bsum      = (int*)wsp;

        hipMemsetAsync(cnt, 0, (size_t)N_TOT * 4, stream);
        count_kernel<<<2048, 256, 0, stream>>>(grow, cnt, nnz);
        scan_block_sums<<<nb2, 256, 0, stream>>>(cnt, bsum, N_TOT);
        scan_bsum_kernel<<<1, 64, 0, stream>>>(bsum, nb2);
        scan_final<<<nb2, 256, 0, stream>>>(cnt, bsum, row_start, N_TOT, nnz);
        hipMemsetAsync(cnt, 0, (size_t)N_TOT * 4, stream);
        fill_kernel<<<2048, 256, 0, stream>>>(grow, gcol, gval, row_start, cnt, eg, nnz);
        gather16_kernel<<<g16_grid, 256, 0, stream>>>(users, items, unb, uw, inb, iw,
                                                      row_start, eg, out);
    } else {
        int grid = (int)(((long long)N_TOT * 64 + 255) / 256);
        base_neighbor_kernel<<<grid, 256, 0, stream>>>(users, items, unb, uw, inb, iw, out);
        long long ethreads = (long long)nnz * 64;
        long long egrid = (ethreads + 255) / 256;
        edge_scatter_kernel<<<(int)egrid, 256, 0, stream>>>(users, items, grow, gcol, gval, out, nnz);
    }
}

// Round 9
// 561.960 us; speedup vs baseline: 1.4956x; 1.0678x over previous
//
#include <hip/hip_runtime.h>

#define N_USER 100000
#define N_ITEM 200000
#define N_TOT  (N_USER + N_ITEM)
#define D      64
#define RPB    64                        // rows per bucket
#define NB     ((N_TOT + RPB - 1) / RPB) // 4688 buckets
#define NBLK_A 256                       // blocks for hist/bin passes
#define THR_A  512
#define CAP    2304                      // edges staged in LDS per chunk (mean bucket = 2048)
#define SCAN_CHUNK 2048                  // tier-2 scan: 256 threads x 8

__device__ __forceinline__ unsigned short f2bf(float f) {
    unsigned b = __float_as_uint(f);
    unsigned r = (b + 0x7FFFu + ((b >> 16) & 1u)) >> 16;   // round-to-nearest-even
    return (unsigned short)r;
}
__device__ __forceinline__ float bf2f(unsigned short u) {
    return __uint_as_float(((unsigned)u) << 16);
}

// ================= emb -> bf16 conversion =================
__global__ __launch_bounds__(256) void conv_kernel(const float* __restrict__ users,
                                                   const float* __restrict__ items,
                                                   ushort* __restrict__ emb16) {
    size_t i = (size_t)blockIdx.x * blockDim.x + threadIdx.x;   // quad index
    const size_t total = (size_t)N_TOT * D / 4;
    if (i >= total) return;
    size_t e0 = i * 4;
    const size_t usz = (size_t)N_USER * D;
    const float* src = (e0 < usz) ? users + e0 : items + (e0 - usz);
    float4 v = *reinterpret_cast<const float4*>(src);
    ushort4 o;
    o.x = f2bf(v.x); o.y = f2bf(v.y); o.z = f2bf(v.z); o.w = f2bf(v.w);
    *reinterpret_cast<ushort4*>(emb16 + e0) = o;
}

// ================= bucket binning (RPB=64) =================

__global__ __launch_bounds__(THR_A) void hist_kernel(const int* __restrict__ rows,
                                                     int* __restrict__ hist, int nnz, int chunk) {
    __shared__ int h[NB];
    for (int k = threadIdx.x; k < NB; k += blockDim.x) h[k] = 0;
    __syncthreads();
    int lo = blockIdx.x * chunk;
    int hi = min(lo + chunk, nnz);
    for (int i = lo + threadIdx.x; i < hi; i += blockDim.x)
        atomicAdd(&h[rows[i] >> 6], 1);
    __syncthreads();
    for (int k = threadIdx.x; k < NB; k += blockDim.x)
        hist[(size_t)blockIdx.x * NB + k] = h[k];
}

__global__ void bucket_tot_kernel(const int* __restrict__ hist, int* __restrict__ tot) {
    int k = blockIdx.x * blockDim.x + threadIdx.x;
    if (k >= NB) return;
    int s = 0;
    for (int b = 0; b < NBLK_A; ++b) s += hist[(size_t)b * NB + k];
    tot[k] = s;
}

__global__ __launch_bounds__(1024) void scan_kernel(const int* __restrict__ tot,
                                                    int* __restrict__ bstart, int nnz) {
    __shared__ int s[1024];
    const int t = threadIdx.x;
    const int PER = (NB + 1023) / 1024;   // 5
    int loc[8];
    int sum = 0;
    #pragma unroll
    for (int k = 0; k < PER; ++k) {
        int idx = t * PER + k;
        int v = (idx < NB) ? tot[idx] : 0;
        loc[k] = sum; sum += v;
    }
    s[t] = sum;
    __syncthreads();
    for (int off = 1; off < 1024; off <<= 1) {
        int v = (t >= off) ? s[t - off] : 0;
        __syncthreads();
        s[t] += v;
        __syncthreads();
    }
    int base = s[t] - sum;  // exclusive
    #pragma unroll
    for (int k = 0; k < PER; ++k) {
        int idx = t * PER + k;
        if (idx < NB) bstart[idx] = base + loc[k];
    }
    if (t == 1023) bstart[NB] = nnz;
}

__global__ void blockbase_kernel(int* __restrict__ hist, const int* __restrict__ bstart) {
    int k = blockIdx.x * blockDim.x + threadIdx.x;
    if (k >= NB) return;
    int base = bstart[k];
    for (int b = 0; b < NBLK_A; ++b) {
        size_t idx = (size_t)b * NB + k;
        int v = hist[idx];
        hist[idx] = base;
        base += v;
    }
}

__global__ __launch_bounds__(THR_A) void bin_kernel(const int* __restrict__ rows,
                                                    const int* __restrict__ cols,
                                                    const float* __restrict__ vals,
                                                    const int* __restrict__ hist,
                                                    uint2* __restrict__ eg, int nnz, int chunk) {
    __shared__ int cur[NB];
    for (int k = threadIdx.x; k < NB; k += blockDim.x)
        cur[k] = hist[(size_t)blockIdx.x * NB + k];
    __syncthreads();
    int lo = blockIdx.x * chunk;
    int hi = min(lo + chunk, nnz);
    for (int i = lo + threadIdx.x; i < hi; i += blockDim.x) {
        int r = rows[i];
        int k = r >> 6;
        int slot = atomicAdd(&cur[k], 1);
        uint2 p;
        p.x = ((unsigned)(r & 63) << 19) | (unsigned)cols[i];
        p.y = __float_as_uint(vals[i]);
        eg[slot] = p;
    }
}

// ======= fused: in-LDS row sort + base + neighbor + gather, one block per bucket =======
__global__ __launch_bounds__(256) void sortgather_kernel(
    const float* __restrict__ users, const float* __restrict__ items,
    const ushort* __restrict__ emb16,
    const int*   __restrict__ unb,   const float* __restrict__ uw,
    const int*   __restrict__ inb,   const float* __restrict__ iw,
    const int*   __restrict__ bstart, const uint2* __restrict__ eg,
    float* __restrict__ out)
{
    __shared__ uint2 lds_e[CAP];          // 18 KB
    __shared__ int h[RPB], st[RPB], cur[RPB];

    const int tid  = threadIdx.x;
    const int g    = tid >> 4;            // 16 groups
    const int sub  = tid & 15;
    const int d0   = sub * 4;
    const int k    = blockIdx.x;
    const int row0 = k * RPB;

    // base + neighbor into register accumulators: group g owns rows row0 + rr*16 + g
    float4 acc[4];
    #pragma unroll
    for (int rr = 0; rr < 4; ++rr) {
        const int row = row0 + rr * 16 + g;
        if (row >= N_TOT) { acc[rr] = make_float4(0.f, 0.f, 0.f, 0.f); continue; }
        float4 a;
        if (row < N_USER) {
            a = *reinterpret_cast<const float4*>(&users[(size_t)row * D + d0]);
            const int*   nb = unb + (size_t)row * 10;
            const float* w  = uw  + (size_t)row * 10;
            #pragma unroll
            for (int q = 0; q < 10; ++q) {
                ushort4 u = *reinterpret_cast<const ushort4*>(emb16 + (size_t)nb[q] * D + d0);
                float wq = w[q];
                a.x += wq * bf2f(u.x); a.y += wq * bf2f(u.y);
                a.z += wq * bf2f(u.z); a.w += wq * bf2f(u.w);
            }
        } else {
            const int r = row - N_USER;
            a = *reinterpret_cast<const float4*>(&items[(size_t)r * D + d0]);
            const int*   nb = inb + (size_t)r * 10;
            const float* w  = iw  + (size_t)r * 10;
            #pragma unroll
            for (int q = 0; q < 10; ++q) {
                ushort4 u = *reinterpret_cast<const ushort4*>(emb16 + ((size_t)nb[q] + N_USER) * D + d0);
                float wq = w[q];
                a.x += wq * bf2f(u.x); a.y += wq * bf2f(u.y);
                a.z += wq * bf2f(u.z); a.w += wq * bf2f(u.w);
            }
        }
        acc[rr] = a;
    }

    const int s = bstart[k];
    const int e = bstart[k + 1];

    for (int cs = s; cs < e; cs += CAP) {
        const int n = min(e - cs, CAP);

        if (tid < RPB) h[tid] = 0;
        __syncthreads();
        for (int i = tid; i < n; i += 256)
            atomicAdd(&h[eg[cs + i].x >> 19], 1);
        __syncthreads();
        if (tid < RPB) {                  // wave 0: 64-wide shfl scan
            int orig = h[tid];
            int v = orig;
            #pragma unroll
            for (int off = 1; off < RPB; off <<= 1) {
                int u = __shfl_up(v, off);
                if (tid >= off) v += u;
            }
            st[tid]  = v - orig;
            cur[tid] = v - orig;
        }
        __syncthreads();
        for (int i = tid; i < n; i += 256) {
            uint2 p = eg[cs + i];         // L2 hit (read in hist pass just above)
            int slot = atomicAdd(&cur[p.x >> 19], 1);
            lds_e[slot] = p;
        }
        __syncthreads();

        #pragma unroll
        for (int rr = 0; rr < 4; ++rr) {
            const int r  = rr * 16 + g;
            const int b0 = st[r];
            const int cr = h[r];
            int j = 0;
            for (; j + 3 < cr; j += 4) {
                uint2 p0 = lds_e[b0 + j],     p1 = lds_e[b0 + j + 1];
                uint2 p2 = lds_e[b0 + j + 2], p3 = lds_e[b0 + j + 3];
                ushort4 u0 = *reinterpret_cast<const ushort4*>(emb16 + (size_t)(p0.x & 0x7FFFFu) * D + d0);
                ushort4 u1 = *reinterpret_cast<const ushort4*>(emb16 + (size_t)(p1.x & 0x7FFFFu) * D + d0);
                ushort4 u2 = *reinterpret_cast<const ushort4*>(emb16 + (size_t)(p2.x & 0x7FFFFu) * D + d0);
                ushort4 u3 = *reinterpret_cast<const ushort4*>(emb16 + (size_t)(p3.x & 0x7FFFFu) * D + d0);
                float a0 = __uint_as_float(p0.y), a1 = __uint_as_float(p1.y);
                float a2 = __uint_as_float(p2.y), a3 = __uint_as_float(p3.y);
                acc[rr].x += a0 * bf2f(u0.x); acc[rr].y += a0 * bf2f(u0.y);
                acc[rr].z += a0 * bf2f(u0.z); acc[rr].w += a0 * bf2f(u0.w);
                acc[rr].x += a1 * bf2f(u1.x); acc[rr].y += a1 * bf2f(u1.y);
                acc[rr].z += a1 * bf2f(u1.z); acc[rr].w += a1 * bf2f(u1.w);
                acc[rr].x += a2 * bf2f(u2.x); acc[rr].y += a2 * bf2f(u2.y);
                acc[rr].z += a2 * bf2f(u2.z); acc[rr].w += a2 * bf2f(u2.w);
                acc[rr].x += a3 * bf2f(u3.x); acc[rr].y += a3 * bf2f(u3.y);
                acc[rr].z += a3 * bf2f(u3.z); acc[rr].w += a3 * bf2f(u3.w);
            }
            for (; j < cr; ++j) {
                uint2 p = lds_e[b0 + j];
                ushort4 u = *reinterpret_cast<const ushort4*>(emb16 + (size_t)(p.x & 0x7FFFFu) * D + d0);
                float a = __uint_as_float(p.y);
                acc[rr].x += a * bf2f(u.x); acc[rr].y += a * bf2f(u.y);
                acc[rr].z += a * bf2f(u.z); acc[rr].w += a * bf2f(u.w);
            }
        }
        __syncthreads();                  // protect h/st/lds_e before next chunk
    }

    #pragma unroll
    for (int rr = 0; rr < 4; ++rr) {
        const int row = row0 + rr * 16 + g;
        if (row < N_TOT)
            *reinterpret_cast<float4*>(&out[(size_t)row * D + d0]) = acc[rr];
    }
}

// ================= tier-2: CSR build via global atomics + fp32 gather =================

__global__ void count_kernel(const int* __restrict__ rows, int* __restrict__ cnt, int nnz) {
    int i = blockIdx.x * blockDim.x + threadIdx.x;
    int stride = gridDim.x * blockDim.x;
    for (; i < nnz; i += stride) atomicAdd(&cnt[rows[i]], 1);
}

__global__ void scan_block_sums(const int* __restrict__ cnt, int* __restrict__ bsum, int n) {
    __shared__ int sdata[256];
    int base = blockIdx.x * SCAN_CHUNK;
    int s = 0;
    for (int t = threadIdx.x; t < SCAN_CHUNK; t += 256) {
        int idx = base + t;
        s += (idx < n) ? cnt[idx] : 0;
    }
    sdata[threadIdx.x] = s;
    __syncthreads();
    for (int off = 128; off > 0; off >>= 1) {
        if (threadIdx.x < off) sdata[threadIdx.x] += sdata[threadIdx.x + off];
        __syncthreads();
    }
    if (threadIdx.x == 0) bsum[blockIdx.x] = sdata[0];
}

__global__ void scan_bsum_kernel(int* __restrict__ bsum, int nb) {
    if (threadIdx.x == 0 && blockIdx.x == 0) {
        int acc = 0;
        for (int i = 0; i < nb; ++i) { int v = bsum[i]; bsum[i] = acc; acc += v; }
    }
}

__global__ void scan_final(const int* __restrict__ cnt, const int* __restrict__ bsum,
                           int* __restrict__ row_start, int n, int nnz) {
    __shared__ int sums[256];
    int b = blockIdx.x, t = threadIdx.x;
    int base = b * SCAN_CHUNK;
    int loc[8];
    int s = 0;
    #pragma unroll
    for (int k = 0; k < 8; ++k) {
        int idx = base + t * 8 + k;
        int v = (idx < n) ? cnt[idx] : 0;
        loc[k] = s; s += v;
    }
    sums[t] = s;
    __syncthreads();
    for (int off = 1; off < 256; off <<= 1) {
        int v = (t >= off) ? sums[t - off] : 0;
        __syncthreads();
        sums[t] += v;
        __syncthreads();
    }
    int off0 = bsum[b] + (sums[t] - s);
    #pragma unroll
    for (int k = 0; k < 8; ++k) {
        int idx = base + t * 8 + k;
        if (idx < n) row_start[idx] = off0 + loc[k];
    }
    if (b == gridDim.x - 1 && t == 255) row_start[n] = nnz;
}

__global__ void fill_kernel(const int* __restrict__ rows, const int* __restrict__ cols,
                            const float* __restrict__ vals, const int* __restrict__ row_start,
                            int* __restrict__ pos, uint2* __restrict__ eg, int nnz) {
    int i = blockIdx.x * blockDim.x + threadIdx.x;
    int stride = gridDim.x * blockDim.x;
    for (; i < nnz; i += stride) {
        int r = rows[i];
        int p = atomicAdd(&pos[r], 1);
        uint2 e;
        e.x = (unsigned)cols[i];
        e.y = __float_as_uint(vals[i]);
        eg[row_start[r] + p] = e;
    }
}

__global__ __launch_bounds__(256) void gather16_kernel(
    const float* __restrict__ users, const float* __restrict__ items,
    const int*   __restrict__ unb,   const float* __restrict__ uw,
    const int*   __restrict__ inb,   const float* __restrict__ iw,
    const int*   __restrict__ row_start, const uint2* __restrict__ eg,
    float* __restrict__ out)
{
    const int tid = threadIdx.x;
    const int grp = tid >> 4;
    const int sub = tid & 15;
    const int row = blockIdx.x * 16 + grp;
    if (row >= N_TOT) return;
    const int d0 = sub * 4;

    float4 acc;
    if (row < N_USER) {
        acc = *reinterpret_cast<const float4*>(&users[(size_t)row * D + d0]);
        const int*   nb = unb + (size_t)row * 10;
        const float* w  = uw  + (size_t)row * 10;
        #pragma unroll
        for (int q = 0; q < 10; ++q) {
            float4 v = *reinterpret_cast<const float4*>(&users[(size_t)nb[q] * D + d0]);
            float wq = w[q];
            acc.x += wq * v.x; acc.y += wq * v.y; acc.z += wq * v.z; acc.w += wq * v.w;
        }
    } else {
        int r = row - N_USER;
        acc = *reinterpret_cast<const float4*>(&items[(size_t)r * D + d0]);
        const int*   nb = inb + (size_t)r * 10;
        const float* w  = iw  + (size_t)r * 10;
        #pragma unroll
        for (int q = 0; q < 10; ++q) {
            float4 v = *reinterpret_cast<const float4*>(&items[(size_t)nb[q] * D + d0]);
            float wq = w[q];
            acc.x += wq * v.x; acc.y += wq * v.y; acc.z += wq * v.z; acc.w += wq * v.w;
        }
    }

    const int s = row_start[row];
    const int e = row_start[row + 1];
    int i = s;
    for (; i + 3 < e; i += 4) {
        uint2 p0 = eg[i], p1 = eg[i + 1], p2 = eg[i + 2], p3 = eg[i + 3];
        int c0 = (int)(p0.x & 0x7FFFFu), c1 = (int)(p1.x & 0x7FFFFu);
        int c2 = (int)(p2.x & 0x7FFFFu), c3 = (int)(p3.x & 0x7FFFFu);
        const float* s0 = (c0 < N_USER) ? users + (size_t)c0 * D : items + (size_t)(c0 - N_USER) * D;
        const float* s1 = (c1 < N_USER) ? users + (size_t)c1 * D : items + (size_t)(c1 - N_USER) * D;
        const float* s2 = (c2 < N_USER) ? users + (size_t)c2 * D : items + (size_t)(c2 - N_USER) * D;
        const float* s3 = (c3 < N_USER) ? users + (size_t)c3 * D : items + (size_t)(c3 - N_USER) * D;
        float4 v0 = *reinterpret_cast<const float4*>(s0 + d0);
        float4 v1 = *reinterpret_cast<const float4*>(s1 + d0);
        float4 v2 = *reinterpret_cast<const float4*>(s2 + d0);
        float4 v3 = *reinterpret_cast<const float4*>(s3 + d0);
        float a0 = __uint_as_float(p0.y), a1 = __uint_as_float(p1.y);
        float a2 = __uint_as_float(p2.y), a3 = __uint_as_float(p3.y);
        acc.x += a0 * v0.x; acc.y += a0 * v0.y; acc.z += a0 * v0.z; acc.w += a0 * v0.w;
        acc.x += a1 * v1.x; acc.y += a1 * v1.y; acc.z += a1 * v1.z; acc.w += a1 * v1.w;
        acc.x += a2 * v2.x; acc.y += a2 * v2.y; acc.z += a2 * v2.z; acc.w += a2 * v2.w;
        acc.x += a3 * v3.x; acc.y += a3 * v3.y; acc.z += a3 * v3.z; acc.w += a3 * v3.w;
    }
    for (; i < e; ++i) {
        uint2 p = eg[i];
        int c = (int)(p.x & 0x7FFFFu);
        const float* src = (c < N_USER) ? users + (size_t)c * D : items + (size_t)(c - N_USER) * D;
        float4 v = *reinterpret_cast<const float4*>(src + d0);
        float a = __uint_as_float(p.y);
        acc.x += a * v.x; acc.y += a * v.y; acc.z += a * v.z; acc.w += a * v.w;
    }

    *reinterpret_cast<float4*>(&out[(size_t)row * D + d0]) = acc;
}

// ================= tier-3 fallback: scatter =================
__global__ __launch_bounds__(256) void base_neighbor_kernel(
    const float* __restrict__ users, const float* __restrict__ items,
    const int*   __restrict__ unb,   const float* __restrict__ uw,
    const int*   __restrict__ inb,   const float* __restrict__ iw,
    float* __restrict__ out)
{
    int gtid = blockIdx.x * blockDim.x + threadIdx.x;
    int row  = gtid >> 6;
    int lane = gtid & 63;
    if (row >= N_TOT) return;
    float acc;
    if (row < N_USER) {
        acc = users[(size_t)row * D + lane];
        const int*   nb = unb + (size_t)row * 10;
        const float* w  = uw  + (size_t)row * 10;
        #pragma unroll
        for (int q = 0; q < 10; ++q) acc += w[q] * users[(size_t)nb[q] * D + lane];
    } else {
        int r = row - N_USER;
        acc = items[(size_t)r * D + lane];
        const int*   nb = inb + (size_t)r * 10;
        const float* w  = iw  + (size_t)r * 10;
        #pragma unroll
        for (int q = 0; q < 10; ++q) acc += w[q] * items[(size_t)nb[q] * D + lane];
    }
    out[(size_t)row * D + lane] = acc;
}

__global__ __launch_bounds__(256) void edge_scatter_kernel(
    const float* __restrict__ users, const float* __restrict__ items,
    const int*   __restrict__ rows,  const int* __restrict__ cols,
    const float* __restrict__ vals,
    float* __restrict__ out, int nnz)
{
    int gtid = blockIdx.x * blockDim.x + threadIdx.x;
    int e    = gtid >> 6;
    int lane = gtid & 63;
    if (e >= nnz) return;
    int   r = rows[e];
    int   c = cols[e];
    float v = vals[e];
    const float* src = (c < N_USER) ? (users + (size_t)c * D)
                                    : (items + (size_t)(c - N_USER) * D);
    atomicAdd(&out[(size_t)r * D + lane], v * src[lane]);
}

extern "C" void kernel_launch(void* const* d_in, const int* in_sizes, int n_in,
                              void* d_out, int out_size, void* d_ws, size_t ws_size,
                              hipStream_t stream) {
    const float* users = (const float*)d_in[0];
    const float* items = (const float*)d_in[1];
    const int*   unb   = (const int*)  d_in[2];
    const float* uw    = (const float*)d_in[3];
    const int*   inb   = (const int*)  d_in[4];
    const float* iw    = (const float*)d_in[5];
    const int*   grow  = (const int*)  d_in[6];
    const int*   gcol  = (const int*)  d_in[7];
    const float* gval  = (const float*)d_in[8];
    float* out = (float*)d_out;

    const int nnz = in_sizes[6];

    const size_t A = 255;
    const size_t sz_eg       = (((size_t)nnz * 8) + A) & ~A;
    const size_t sz_hist     = (((size_t)NBLK_A * NB * 4) + A) & ~A;
    const size_t sz_tot      = (((size_t)NB * 4) + A) & ~A;
    const size_t sz_bstart   = (((size_t)(NB + 1) * 4) + A) & ~A;
    const size_t sz_rowstart = (((size_t)(N_TOT + 1) * 4) + A) & ~A;
    const size_t sz_emb16    = (((size_t)N_TOT * D * 2) + A) & ~A;
    const size_t need0 = sz_eg + sz_hist + sz_tot + sz_bstart + sz_emb16;

    const size_t sz_cnt  = (((size_t)N_TOT * 4) + A) & ~A;
    const int    nb2     = (N_TOT + SCAN_CHUNK - 1) / SCAN_CHUNK;
    const size_t sz_bsum = (((size_t)nb2 * 4) + A) & ~A;
    const size_t need2 = sz_eg + sz_rowstart + sz_cnt + sz_bsum;

    if (ws_size >= need0) {
        char* wsp = (char*)d_ws;
        uint2*  eg        = (uint2*)wsp;  wsp += sz_eg;
        int*    hist      = (int*)wsp;    wsp += sz_hist;
        int*    tot       = (int*)wsp;    wsp += sz_tot;
        int*    bstart    = (int*)wsp;    wsp += sz_bstart;
        ushort* emb16     = (ushort*)wsp;

        const int chunk = (nnz + NBLK_A - 1) / NBLK_A;
        const int conv_grid = (int)(((size_t)N_TOT * D / 4 + 255) / 256);

        conv_kernel<<<conv_grid, 256, 0, stream>>>(users, items, emb16);
        hist_kernel<<<NBLK_A, THR_A, 0, stream>>>(grow, hist, nnz, chunk);
        bucket_tot_kernel<<<(NB + 255) / 256, 256, 0, stream>>>(hist, tot);
        scan_kernel<<<1, 1024, 0, stream>>>(tot, bstart, nnz);
        blockbase_kernel<<<(NB + 255) / 256, 256, 0, stream>>>(hist, bstart);
        bin_kernel<<<NBLK_A, THR_A, 0, stream>>>(grow, gcol, gval, hist, eg, nnz, chunk);
        sortgather_kernel<<<NB, 256, 0, stream>>>(users, items, emb16, unb, uw, inb, iw,
                                                  bstart, eg, out);
    } else if (ws_size >= need2) {
        char* wsp = (char*)d_ws;
        uint2* eg        = (uint2*)wsp;  wsp += sz_eg;
        int*   row_start = (int*)wsp;    wsp += sz_rowstart;
        int*   cnt       = (int*)wsp;    wsp += sz_cnt;
        int*   bsum      = (int*)wsp;

        hipMemsetAsync(cnt, 0, (size_t)N_TOT * 4, stream);
        count_kernel<<<2048, 256, 0, stream>>>(grow, cnt, nnz);
        scan_block_sums<<<nb2, 256, 0, stream>>>(cnt, bsum, N_TOT);
        scan_bsum_kernel<<<1, 64, 0, stream>>>(bsum, nb2);
        scan_final<<<nb2, 256, 0, stream>>>(cnt, bsum, row_start, N_TOT, nnz);
        hipMemsetAsync(cnt, 0, (size_t)N_TOT * 4, stream);
        fill_kernel<<<2048, 256, 0, stream>>>(grow, gcol, gval, row_start, cnt, eg, nnz);
        const int g16_grid = (N_TOT + 15) / 16;
        gather16_kernel<<<g16_grid, 256, 0, stream>>>(users, items, unb, uw, inb, iw,
                                                      row_start, eg, out);
    } else {
        int grid = (int)(((long long)N_TOT * 64 + 255) / 256);
        base_neighbor_kernel<<<grid, 256, 0, stream>>>(users, items, unb, uw, inb, iw, out);
        long long ethreads = (long long)nnz * 64;
        long long egrid = (ethreads + 255) / 256;
        edge_scatter_kernel<<<(int)egrid, 256, 0, stream>>>(users, items, grow, gcol, gval, out, nnz);
    }
}